// Round 4
// baseline (465.477 us; speedup 1.0000x reference)
//
#include <hip/hip_runtime.h>
#include <stdint.h>

typedef unsigned short u16;
typedef __attribute__((ext_vector_type(4))) float f32x4;
typedef __attribute__((ext_vector_type(8))) short bf16x8;
typedef __attribute__((ext_vector_type(4))) uint32_t u32x4;

#define D_MODEL 2048
#define NHEADS 16
#define HD 128
#define BSZ 2
#define TQ 1024
#define XL 1024
#define KVLEN 2048
#define QKVW 6144  // 3*D_MODEL

__device__ __forceinline__ float b2f(u16 u) {
  union { uint32_t i; float f; } x; x.i = ((uint32_t)u) << 16; return x.f;
}
__device__ __forceinline__ u16 f2b(float f) {
  union { float f; uint32_t i; } x; x.f = f;
  uint32_t r = x.i + 0x7FFFu + ((x.i >> 16) & 1u);  // RNE
  return (u16)(r >> 16);
}

union U4 { u32x4 u; u16 s[8]; };

__device__ __forceinline__ float rmax16(float v) {
  v = fmaxf(v, __shfl_xor(v, 1));
  v = fmaxf(v, __shfl_xor(v, 2));
  v = fmaxf(v, __shfl_xor(v, 4));
  v = fmaxf(v, __shfl_xor(v, 8));
  return v;
}
__device__ __forceinline__ float rsum16(float v) {
  v += __shfl_xor(v, 1);
  v += __shfl_xor(v, 2);
  v += __shfl_xor(v, 4);
  v += __shfl_xor(v, 8);
  return v;
}

// 8 consecutive elements from a fp32 or bf16 source, packed to 8 bf16 (u32x4)
template <bool F32>
struct Pref {
  f32x4 lo, hi;  // F32 path
  u32x4 raw;     // bf16 path
  __device__ __forceinline__ void load(const void* base, size_t elem_off) {
    if (F32) {
      const float* p = (const float*)base + elem_off;
      lo = *(const f32x4*)p;
      hi = *(const f32x4*)(p + 4);
    } else {
      raw = *(const u32x4*)((const u16*)base + elem_off);
    }
  }
  __device__ __forceinline__ u32x4 pack() const {
    if (!F32) return raw;
    U4 o;
    o.s[0] = f2b(lo[0]); o.s[1] = f2b(lo[1]); o.s[2] = f2b(lo[2]); o.s[3] = f2b(lo[3]);
    o.s[4] = f2b(hi[0]); o.s[5] = f2b(hi[1]); o.s[6] = f2b(hi[2]); o.s[7] = f2b(hi[3]);
    return o.u;
  }
};

// ---------------------------------------------------------------------------
// C = A * Bt^T : A (M,K) row-major, Bt (N,K) row-major. Internal compute bf16.
// 128x128 tile, BK=32, 256 thr (4 waves, 2x2), 16x16x32 MFMA, reg prefetch.
// AF32/BF32: operand storage fp32 (converted during staging). CF32: C fp32.
// ---------------------------------------------------------------------------
template <bool AF32, bool BF32, bool CF32>
__global__ __launch_bounds__(256, 2) void gemm_bt(
    const void* __restrict__ Av, const void* __restrict__ Bv, void* __restrict__ Cv,
    int M, int N, int K)
{
  __shared__ u16 sA[128 * 32];
  __shared__ u16 sB[128 * 32];
  const int tid  = threadIdx.x;
  const int lane = tid & 63;
  const int wave = tid >> 6;
  const int quad = lane >> 4;
  const int mcol = lane & 15;
  const int wm = (wave >> 1) * 64;
  const int wn = (wave & 1) * 64;
  const int bm = blockIdx.y * 128;
  const int bn = blockIdx.x * 128;

  f32x4 acc[4][4] = {};

  // chunk c (8 elems) at LDS offset c*8 holds logical (row = c>>2, kq = (c&3)*8)
  const int c0 = tid, c1 = tid + 256;
  size_t a0 = (size_t)(bm + (c0 >> 2)) * K + (c0 & 3) * 8;
  size_t a1 = (size_t)(bm + (c1 >> 2)) * K + (c1 & 3) * 8;
  size_t b0 = (size_t)(bn + (c0 >> 2)) * K + (c0 & 3) * 8;
  size_t b1 = (size_t)(bn + (c1 >> 2)) * K + (c1 & 3) * 8;

  Pref<AF32> ra0, ra1; Pref<BF32> rb0, rb1;
  ra0.load(Av, a0); ra1.load(Av, a1);
  rb0.load(Bv, b0); rb1.load(Bv, b1);

  const int nk = K >> 5;
  for (int kk = 0; kk < nk; ++kk) {
    __syncthreads();  // previous iteration's frag reads complete
    *(u32x4*)&sA[c0 * 8] = ra0.pack();
    *(u32x4*)&sA[c1 * 8] = ra1.pack();
    *(u32x4*)&sB[c0 * 8] = rb0.pack();
    *(u32x4*)&sB[c1 * 8] = rb1.pack();
    __syncthreads();  // staging visible
    if (kk + 1 < nk) {  // prefetch next K-tile, overlaps MFMA
      a0 += 32; a1 += 32; b0 += 32; b1 += 32;
      ra0.load(Av, a0); ra1.load(Av, a1);
      rb0.load(Bv, b0); rb1.load(Bv, b1);
    }
    bf16x8 af[4], bff[4];
#pragma unroll
    for (int i = 0; i < 4; ++i) {
      af[i]  = *(const bf16x8*)&sA[(wm + i * 16 + mcol) * 32 + quad * 8];
      bff[i] = *(const bf16x8*)&sB[(wn + i * 16 + mcol) * 32 + quad * 8];
    }
#pragma unroll
    for (int i = 0; i < 4; ++i)
#pragma unroll
      for (int j = 0; j < 4; ++j)
        acc[i][j] = __builtin_amdgcn_mfma_f32_16x16x32_bf16(af[i], bff[j], acc[i][j], 0, 0, 0);
  }

  // epilogue: C row = quad*4 + reg, col = mcol (m89-verified C/D layout)
#pragma unroll
  for (int i = 0; i < 4; ++i)
#pragma unroll
    for (int r = 0; r < 4; ++r) {
      const int row = bm + wm + i * 16 + quad * 4 + r;
      const size_t base = (size_t)row * N + bn + wn;
#pragma unroll
      for (int j = 0; j < 4; ++j) {
        if (CF32) ((float*)Cv)[base + j * 16 + mcol] = acc[i][j][r];
        else      ((u16*)Cv)[base + j * 16 + mcol] = f2b(acc[i][j][r]);
      }
    }
}

// ---------------------------------------------------------------------------
// vt[b,h,d,kv] = (kv < XL) ? cvt(v_xl[b,kv,h*HD+d]) : qkv[b,kv-XL, 2*D_MODEL+h*HD+d]
// v_xl fp32, qkv bf16 (internal), vt bf16. 64x64 LDS tile transpose.
// ---------------------------------------------------------------------------
__global__ __launch_bounds__(256, 4) void transpose_v(
    const float* __restrict__ v_xl, const u16* __restrict__ qkv, u16* __restrict__ vt)
{
  __shared__ u16 tile[64 * 72];
  const int tid = threadIdx.x;
  const int kv0 = blockIdx.x * 64;
  const int d0  = blockIdx.y * 64;
  const int bh  = blockIdx.z;
  const int b = bh >> 4, h = bh & 15;
#pragma unroll
  for (int j = 0; j < 2; ++j) {
    const int id = tid + 256 * j;
    const int kr = id >> 3, dq = (id & 7) * 8;
    const int kvg = kv0 + kr;
    if (kvg < XL) {
      const float* src = v_xl + ((size_t)b * XL + kvg) * D_MODEL + h * HD + d0 + dq;
      f32x4 lo = *(const f32x4*)src, hi = *(const f32x4*)(src + 4);
      U4 o;
      o.s[0] = f2b(lo[0]); o.s[1] = f2b(lo[1]); o.s[2] = f2b(lo[2]); o.s[3] = f2b(lo[3]);
      o.s[4] = f2b(hi[0]); o.s[5] = f2b(hi[1]); o.s[6] = f2b(hi[2]); o.s[7] = f2b(hi[3]);
      *(u32x4*)&tile[kr * 72 + dq] = o.u;
    } else {
      const u16* src = qkv + ((size_t)b * TQ + (kvg - XL)) * QKVW + 2 * D_MODEL + h * HD + d0 + dq;
      *(u32x4*)&tile[kr * 72 + dq] = *(const u32x4*)src;
    }
  }
  __syncthreads();
#pragma unroll
  for (int j = 0; j < 2; ++j) {
    const int id = tid + 256 * j;
    const int dr = id >> 3, kq = (id & 7) * 8;
    U4 ov;
#pragma unroll
    for (int i = 0; i < 8; ++i) ov.s[i] = tile[(kq + i) * 72 + dr];
    *(u32x4*)&vt[((size_t)bh * HD + d0 + dr) * KVLEN + kv0 + kq] = ov.u;
  }
}

// ---------------------------------------------------------------------------
// Flash attention. grid (8 q-tiles, 32 bh), 256 thr = 4 waves x 32 q-rows.
// kv-tile 128. Rope fused into Q load and K staging; k_xl gets pos_emb (no rope).
// kxl/pos/cos/sin fp32; qkv/vt/y bf16 internal. Plain LDS, stride 136 pad.
// ---------------------------------------------------------------------------
#define LSTR 136  // 128 + 8 pad, keeps 16B alignment of 8-elem chunks

__global__ __launch_bounds__(256, 1) void attn(
    const u16* __restrict__ qkv, const float* __restrict__ kxl,
    const float* __restrict__ pos, const u16* __restrict__ vt,
    const float* __restrict__ cosw, const float* __restrict__ sinw,
    const int* __restrict__ iscausal, u16* __restrict__ y)
{
  __shared__ u16 sK[128 * LSTR];
  __shared__ u16 sV[128 * LSTR];
  __shared__ u16 sP[4 * 32 * LSTR];

  const int tid  = threadIdx.x;
  const int lane = tid & 63;
  const int w    = tid >> 6;
  const int quad = lane >> 4;
  const int mcol = lane & 15;
  const int qt = blockIdx.x;
  const int bh = blockIdx.y;
  const int b = bh >> 4, h = bh & 15;
  const int causal = *iscausal;
  const float SC = 0.08838834764831845f;  // 1/sqrt(128)

  // ---- Q fragments with fused rope (A-layout: m = mcol, k = quad*8 + ks*32)
  bf16x8 qf[2][4];
#pragma unroll
  for (int mt = 0; mt < 2; ++mt) {
    const int trow = qt * 128 + w * 32 + mt * 16 + mcol;
    const u16* qrow = qkv + ((size_t)b * TQ + trow) * QKVW + h * HD;
    const float* crow = cosw + trow * 64;
    const float* srow = sinw + trow * 64;
#pragma unroll
    for (int ks = 0; ks < 4; ++ks) {
      const int d0 = ks * 32 + quad * 8;
      U4 qv; qv.u = *(const u32x4*)(qrow + d0);
      f32x4 cv = *(const f32x4*)(crow + (d0 >> 1));
      f32x4 sv = *(const f32x4*)(srow + (d0 >> 1));
      bf16x8 dst;
#pragma unroll
      for (int p = 0; p < 4; ++p) {
        const float e = b2f(qv.s[2 * p]), o = b2f(qv.s[2 * p + 1]);
        dst[2 * p]     = (short)f2b(e * cv[p] - o * sv[p]);
        dst[2 * p + 1] = (short)f2b(e * sv[p] + o * cv[p]);
      }
      qf[mt][ks] = dst;
    }
  }

  f32x4 oacc[2][8] = {};
  float mrun[2][4], lrun[2][4];
#pragma unroll
  for (int mt = 0; mt < 2; ++mt)
#pragma unroll
    for (int r = 0; r < 4; ++r) { mrun[mt][r] = -3.0e38f; lrun[mt][r] = 0.f; }

  for (int t16 = 0; t16 < 16; ++t16) {
    const int kv0 = t16 * 128;
    __syncthreads();  // previous iteration's LDS reads done before restaging

    // ---- stage K tile (row = kv within tile, col = d)
    if (kv0 < XL) {
#pragma unroll
      for (int j = 0; j < 8; ++j) {
        const int id = tid + 256 * j;
        const int row = id >> 4, d0 = (id & 15) * 8;
        const int kvg = kv0 + row;
        const float* kp = kxl + ((size_t)b * XL + kvg) * D_MODEL + h * HD + d0;
        const float* pp = pos + (size_t)kvg * D_MODEL + h * HD + d0;
        f32x4 kl = *(const f32x4*)kp, kh = *(const f32x4*)(kp + 4);
        f32x4 pl = *(const f32x4*)pp, ph = *(const f32x4*)(pp + 4);
        U4 ov;
#pragma unroll
        for (int p = 0; p < 4; ++p) {
          ov.s[p]     = f2b(kl[p] + pl[p]);
          ov.s[4 + p] = f2b(kh[p] + ph[p]);
        }
        *(u32x4*)&sK[row * LSTR + d0] = ov.u;
      }
    } else {
#pragma unroll
      for (int j = 0; j < 8; ++j) {
        const int id = tid + 256 * j;
        const int row = id >> 4, d0 = (id & 15) * 8;
        const int tq = kv0 - XL + row;
        U4 kv_, ov;
        kv_.u = *(const u32x4*)(qkv + ((size_t)b * TQ + tq) * QKVW + D_MODEL + h * HD + d0);
        f32x4 cv = *(const f32x4*)(cosw + tq * 64 + (d0 >> 1));
        f32x4 sv = *(const f32x4*)(sinw + tq * 64 + (d0 >> 1));
#pragma unroll
        for (int p = 0; p < 4; ++p) {
          const float e = b2f(kv_.s[2 * p]), o = b2f(kv_.s[2 * p + 1]);
          ov.s[2 * p]     = f2b(e * cv[p] - o * sv[p]);
          ov.s[2 * p + 1] = f2b(e * sv[p] + o * cv[p]);
        }
        *(u32x4*)&sK[row * LSTR + d0] = ov.u;
      }
    }
    // ---- stage V^T tile (row = d, col = kv within tile), bf16 source
#pragma unroll
    for (int j = 0; j < 8; ++j) {
      const int id = tid + 256 * j;
      const int dr = id >> 4, c = id & 15;
      const u16* vr = vt + ((size_t)bh * HD + dr) * KVLEN + kv0 + c * 8;
      *(u32x4*)&sV[dr * LSTR + c * 8] = *(const u32x4*)vr;
    }
    __syncthreads();

    // ---- S = Q K^T (per wave: 2 m-tiles x 8 n-tiles x 4 k-steps)
    f32x4 s[2][8] = {};
#pragma unroll
    for (int ks = 0; ks < 4; ++ks) {
      const int cc = ks * 4 + quad;
#pragma unroll
      for (int nt = 0; nt < 8; ++nt) {
        bf16x8 kf = *(const bf16x8*)&sK[(nt * 16 + mcol) * LSTR + cc * 8];
        s[0][nt] = __builtin_amdgcn_mfma_f32_16x16x32_bf16(qf[0][ks], kf, s[0][nt], 0, 0, 0);
        s[1][nt] = __builtin_amdgcn_mfma_f32_16x16x32_bf16(qf[1][ks], kf, s[1][nt], 0, 0, 0);
      }
    }
#pragma unroll
    for (int mt = 0; mt < 2; ++mt)
#pragma unroll
      for (int nt = 0; nt < 8; ++nt)
#pragma unroll
        for (int r = 0; r < 4; ++r) s[mt][nt][r] *= SC;
    if (causal) {
#pragma unroll
      for (int mt = 0; mt < 2; ++mt)
#pragma unroll
        for (int r = 0; r < 4; ++r) {
          const int qi = qt * 128 + w * 32 + mt * 16 + quad * 4 + r;
#pragma unroll
          for (int nt = 0; nt < 8; ++nt) {
            const int ki = kv0 + nt * 16 + mcol;
            if (ki > qi + (KVLEN - TQ)) s[mt][nt][r] = -1.0e30f;
          }
        }
    }

    // ---- online softmax (row = quad*4+r in C layout) + O rescale
    u16* sPw = &sP[w * 32 * LSTR];
#pragma unroll
    for (int mt = 0; mt < 2; ++mt)
#pragma unroll
      for (int r = 0; r < 4; ++r) {
        float tm = -3.0e38f;
#pragma unroll
        for (int nt = 0; nt < 8; ++nt) tm = fmaxf(tm, s[mt][nt][r]);
        tm = rmax16(tm);
        const float mo = mrun[mt][r];
        const float mn = fmaxf(mo, tm);
        mrun[mt][r] = mn;
        const float al = __expf(mo - mn);
        float rs = 0.f;
#pragma unroll
        for (int nt = 0; nt < 8; ++nt) {
          const float p = __expf(s[mt][nt][r] - mn);
          s[mt][nt][r] = p;
          rs += p;
        }
        rs = rsum16(rs);
        lrun[mt][r] = lrun[mt][r] * al + rs;
#pragma unroll
        for (int nd = 0; nd < 8; ++nd) oacc[mt][nd][r] *= al;
      }
    // ---- write P (bf16) into per-wave region (row = q-row in wave, col = kv)
#pragma unroll
    for (int mt = 0; mt < 2; ++mt)
#pragma unroll
      for (int r = 0; r < 4; ++r) {
        const int row = mt * 16 + quad * 4 + r;
#pragma unroll
        for (int nt = 0; nt < 8; ++nt)
          sPw[row * LSTR + nt * 16 + mcol] = f2b(s[mt][nt][r]);
      }
    __syncthreads();  // P visible

    // ---- O += P V
#pragma unroll
    for (int ks = 0; ks < 4; ++ks) {
      const int cc = ks * 4 + quad;
      bf16x8 pa[2];
#pragma unroll
      for (int mt = 0; mt < 2; ++mt)
        pa[mt] = *(const bf16x8*)&sPw[(mt * 16 + mcol) * LSTR + cc * 8];
#pragma unroll
      for (int nd = 0; nd < 8; ++nd) {
        bf16x8 vf = *(const bf16x8*)&sV[(nd * 16 + mcol) * LSTR + cc * 8];
        oacc[0][nd] = __builtin_amdgcn_mfma_f32_16x16x32_bf16(pa[0], vf, oacc[0][nd], 0, 0, 0);
        oacc[1][nd] = __builtin_amdgcn_mfma_f32_16x16x32_bf16(pa[1], vf, oacc[1][nd], 0, 0, 0);
      }
    }
  }

  // ---- epilogue: y[b, t, h*HD + d] = O / l  (bf16 internal)
#pragma unroll
  for (int mt = 0; mt < 2; ++mt)
#pragma unroll
    for (int r = 0; r < 4; ++r) {
      const int trow = qt * 128 + w * 32 + mt * 16 + quad * 4 + r;
      const float inv = 1.0f / lrun[mt][r];
      u16* yr = y + ((size_t)b * TQ + trow) * D_MODEL + h * HD;
#pragma unroll
      for (int nd = 0; nd < 8; ++nd)
        yr[nd * 16 + mcol] = f2b(oacc[mt][nd][r] * inv);
    }
}

// ---------------------------------------------------------------------------
extern "C" void kernel_launch(void* const* d_in, const int* in_sizes, int n_in,
                              void* d_out, int out_size, void* d_ws, size_t ws_size,
                              hipStream_t stream) {
  const float* x      = (const float*)d_in[0];
  const float* cosw   = (const float*)d_in[1];
  const float* sinw   = (const float*)d_in[2];
  const float* k_xl   = (const float*)d_in[3];
  const float* v_xl   = (const float*)d_in[4];
  const float* pos    = (const float*)d_in[5];
  const float* w_qkv  = (const float*)d_in[6];
  const float* w_proj = (const float*)d_in[7];
  const int* isc      = (const int*)d_in[8];
  float* out = (float*)d_out;

  char* ws = (char*)d_ws;
  u16* qkv_ws = (u16*)ws;                                 // 2*1024*6144*2  = 25165824 B
  u16* vt_ws  = (u16*)(ws + (size_t)25165824);            // 32*128*2048*2  = 16777216 B
  u16* y_ws   = (u16*)(ws + (size_t)25165824 + 16777216); // 2*1024*2048*2  = 8388608 B

  // 1) qkv = x @ w_qkv^T (fp32 in, bf16 out)  M=2048, N=6144, K=2048
  dim3 g1(6144 / 128, 2048 / 128);
  gemm_bt<true, true, false><<<g1, 256, 0, stream>>>(x, w_qkv, qkv_ws, 2048, 6144, 2048);

  // 2) V^T workspace (bf16)
  dim3 gt(KVLEN / 64, HD / 64, BSZ * NHEADS);
  transpose_v<<<gt, 256, 0, stream>>>(v_xl, qkv_ws, vt_ws);

  // 3) flash attention (rope + pos_emb fused) -> y bf16 (b,t,c)
  dim3 ga(TQ / 128, BSZ * NHEADS);
  attn<<<ga, 256, 0, stream>>>(qkv_ws, k_xl, pos, vt_ws, cosw, sinw, isc, y_ws);

  // 4) out = y @ w_proj^T (bf16 x fp32 -> fp32)  M=2048, N=2048, K=2048
  dim3 g2(2048 / 128, 2048 / 128);
  gemm_bt<false, true, true><<<g2, 256, 0, stream>>>(y_ws, w_proj, out, 2048, 2048, 2048);
}

// Round 5
// 390.352 us; speedup vs baseline: 1.1925x; 1.1925x over previous
//
#include <hip/hip_runtime.h>
#include <stdint.h>

typedef unsigned short u16;
typedef __attribute__((ext_vector_type(4))) float f32x4;
typedef __attribute__((ext_vector_type(8))) short bf16x8;
typedef __attribute__((ext_vector_type(4))) uint32_t u32x4;

#define D_MODEL 2048
#define NHEADS 16
#define HD 128
#define BSZ 2
#define TQ 1024
#define XL 1024
#define KVLEN 2048

__device__ __forceinline__ float b2f(u16 u) {
  union { uint32_t i; float f; } x; x.i = ((uint32_t)u) << 16; return x.f;
}
__device__ __forceinline__ u16 f2b(float f) {
  union { float f; uint32_t i; } x; x.f = f;
  uint32_t r = x.i + 0x7FFFu + ((x.i >> 16) & 1u);  // RNE
  return (u16)(r >> 16);
}

union U4 { u32x4 u; u16 s[8]; };

__device__ __forceinline__ void async_copy16(const u16* g, u16* l) {
  __builtin_amdgcn_global_load_lds((__attribute__((address_space(1))) void*)g,
                                   (__attribute__((address_space(3))) void*)l,
                                   16, 0, 0);
}

__device__ __forceinline__ float rmax16(float v) {
  v = fmaxf(v, __shfl_xor(v, 1));
  v = fmaxf(v, __shfl_xor(v, 2));
  v = fmaxf(v, __shfl_xor(v, 4));
  v = fmaxf(v, __shfl_xor(v, 8));
  return v;
}
__device__ __forceinline__ float rsum16(float v) {
  v += __shfl_xor(v, 1);
  v += __shfl_xor(v, 2);
  v += __shfl_xor(v, 4);
  v += __shfl_xor(v, 8);
  return v;
}

struct PrefF32 {  // 8 fp32 -> 8 bf16 pack
  f32x4 lo, hi;
  __device__ __forceinline__ void load(const float* base, size_t off) {
    lo = *(const f32x4*)(base + off);
    hi = *(const f32x4*)(base + off + 4);
  }
  __device__ __forceinline__ u32x4 pack() const {
    U4 o;
    o.s[0] = f2b(lo[0]); o.s[1] = f2b(lo[1]); o.s[2] = f2b(lo[2]); o.s[3] = f2b(lo[3]);
    o.s[4] = f2b(hi[0]); o.s[5] = f2b(hi[1]); o.s[6] = f2b(hi[2]); o.s[7] = f2b(hi[3]);
    return o.u;
  }
};

// ---------------------------------------------------------------------------
// fp32 -> bf16 elementwise, 8 elems/thread
// ---------------------------------------------------------------------------
__global__ __launch_bounds__(256, 4) void cvt_bf16(
    const float* __restrict__ src, u16* __restrict__ dst)
{
  const size_t id = (size_t)blockIdx.x * 256 + threadIdx.x;
  PrefF32 p; p.load(src, id * 8);
  *(u32x4*)&dst[id * 8] = p.pack();
}

// ---------------------------------------------------------------------------
// C = A * Bt^T, bf16 MFMA internal. 128x128 tile, BK=32, 256 thr (2x2 waves).
// AF32/BF32: fp32 operand staged via reg-pack; else bf16 via global_load_lds.
// CSPLIT: C bf16 routed to one of 3 buffers (stride 2048) by bn; else C fp32.
// ---------------------------------------------------------------------------
template <bool AF32, bool BF32, bool CSPLIT>
__global__ __launch_bounds__(256, 2) void gemm_bt(
    const void* __restrict__ Av, const void* __restrict__ Bv,
    void* __restrict__ C0, void* __restrict__ C1, void* __restrict__ C2,
    int M, int N, int K)
{
  __shared__ u16 sA[128 * 32];
  __shared__ u16 sB[128 * 32];
  const int tid  = threadIdx.x;
  const int lane = tid & 63;
  const int wave = tid >> 6;
  const int quad = lane >> 4;
  const int mcol = lane & 15;
  const int wm = (wave >> 1) * 64;
  const int wn = (wave & 1) * 64;
  const int bm = blockIdx.y * 128;
  const int bnE = blockIdx.x * 128;

  f32x4 acc[4][4] = {};

  // chunk c (8 elems, 16B) at LDS c*8: row = c>>2, kq = (c&3)*8
  const int c0 = tid, c1 = tid + 256;
  size_t a0 = (size_t)(bm + (c0 >> 2)) * K + (c0 & 3) * 8;
  size_t a1 = (size_t)(bm + (c1 >> 2)) * K + (c1 & 3) * 8;
  size_t b0 = (size_t)(bnE + (c0 >> 2)) * K + (c0 & 3) * 8;
  size_t b1 = (size_t)(bnE + (c1 >> 2)) * K + (c1 & 3) * 8;

  PrefF32 pa0, pa1, pb0, pb1;
  if (AF32) { pa0.load((const float*)Av, a0); pa1.load((const float*)Av, a1); }
  if (BF32) { pb0.load((const float*)Bv, b0); pb1.load((const float*)Bv, b1); }

  const int nk = K >> 5;
  for (int kk = 0; kk < nk; ++kk) {
    // stage into LDS: async for bf16 operands, reg-pack write for fp32
    if (!AF32) {
      async_copy16((const u16*)Av + a0, &sA[c0 * 8]);
      async_copy16((const u16*)Av + a1, &sA[c1 * 8]);
      a0 += 32; a1 += 32;
    } else {
      *(u32x4*)&sA[c0 * 8] = pa0.pack();
      *(u32x4*)&sA[c1 * 8] = pa1.pack();
    }
    if (!BF32) {
      async_copy16((const u16*)Bv + b0, &sB[c0 * 8]);
      async_copy16((const u16*)Bv + b1, &sB[c1 * 8]);
      b0 += 32; b1 += 32;
    } else {
      *(u32x4*)&sB[c0 * 8] = pb0.pack();
      *(u32x4*)&sB[c1 * 8] = pb1.pack();
    }
    __syncthreads();  // staging visible (barrier drains vmcnt+lgkmcnt)
    if (kk + 1 < nk) {  // prefetch next fp32 tiles into regs (overlaps MFMA)
      if (AF32) { a0 += 32; a1 += 32; pa0.load((const float*)Av, a0); pa1.load((const float*)Av, a1); }
      if (BF32) { b0 += 32; b1 += 32; pb0.load((const float*)Bv, b0); pb1.load((const float*)Bv, b1); }
    }
    bf16x8 af[4], bff[4];
#pragma unroll
    for (int i = 0; i < 4; ++i) {
      af[i]  = *(const bf16x8*)&sA[(wm + i * 16 + mcol) * 32 + quad * 8];
      bff[i] = *(const bf16x8*)&sB[(wn + i * 16 + mcol) * 32 + quad * 8];
    }
#pragma unroll
    for (int i = 0; i < 4; ++i)
#pragma unroll
      for (int j = 0; j < 4; ++j)
        acc[i][j] = __builtin_amdgcn_mfma_f32_16x16x32_bf16(af[i], bff[j], acc[i][j], 0, 0, 0);
    __syncthreads();  // frag reads done before next staging
  }

  // epilogue: C row = quad*4 + reg, col = mcol (m89-verified C/D layout)
  if (CSPLIT) {
    const int sel = bnE >> 11;
    u16* Cp = (u16*)(sel == 0 ? C0 : (sel == 1 ? C1 : C2));
    const int bnl = (bnE & 2047) + wn;
#pragma unroll
    for (int i = 0; i < 4; ++i)
#pragma unroll
      for (int r = 0; r < 4; ++r) {
        const size_t base = (size_t)(bm + wm + i * 16 + quad * 4 + r) * 2048 + bnl;
#pragma unroll
        for (int j = 0; j < 4; ++j)
          Cp[base + j * 16 + mcol] = f2b(acc[i][j][r]);
      }
  } else {
    float* Cp = (float*)C0;
#pragma unroll
    for (int i = 0; i < 4; ++i)
#pragma unroll
      for (int r = 0; r < 4; ++r) {
        const size_t base = (size_t)(bm + wm + i * 16 + quad * 4 + r) * N + bnE + wn;
#pragma unroll
        for (int j = 0; j < 4; ++j)
          Cp[base + j * 16 + mcol] = acc[i][j][r];
      }
  }
}

// ---------------------------------------------------------------------------
// kfull[b,h,kv,d]: kv<XL -> bf16(kxl + pos); kv>=XL -> rope(kbuf) with cos/sin.
// 8 elems/thread. 1,048,576 threads.
// ---------------------------------------------------------------------------
__global__ __launch_bounds__(256, 4) void prep_k(
    const float* __restrict__ kxl, const float* __restrict__ pos,
    const u16* __restrict__ kbuf, const float* __restrict__ cosw,
    const float* __restrict__ sinw, u16* __restrict__ kfull)
{
  const int id = blockIdx.x * 256 + threadIdx.x;
  const int dc = id & 15;
  const int kv = (id >> 4) & 2047;
  const int bh = id >> 15;
  const int b = bh >> 4, h = bh & 15;
  const int d0 = dc * 8;
  U4 o;
  if (kv < XL) {
    const float* kp = kxl + ((size_t)b * XL + kv) * D_MODEL + h * HD + d0;
    const float* pp = pos + (size_t)kv * D_MODEL + h * HD + d0;
    f32x4 kl = *(const f32x4*)kp, kh = *(const f32x4*)(kp + 4);
    f32x4 pl = *(const f32x4*)pp, ph = *(const f32x4*)(pp + 4);
#pragma unroll
    for (int p = 0; p < 4; ++p) {
      o.s[p]     = f2b(kl[p] + pl[p]);
      o.s[4 + p] = f2b(kh[p] + ph[p]);
    }
  } else {
    const int tq = kv - XL;
    U4 kv_;
    kv_.u = *(const u32x4*)(kbuf + ((size_t)b * TQ + tq) * D_MODEL + h * HD + d0);
    f32x4 cv = *(const f32x4*)(cosw + tq * 64 + (d0 >> 1));
    f32x4 sv = *(const f32x4*)(sinw + tq * 64 + (d0 >> 1));
#pragma unroll
    for (int p = 0; p < 4; ++p) {
      const float e = b2f(kv_.s[2 * p]), od = b2f(kv_.s[2 * p + 1]);
      o.s[2 * p]     = f2b(e * cv[p] - od * sv[p]);
      o.s[2 * p + 1] = f2b(e * sv[p] + od * cv[p]);
    }
  }
  *(u32x4*)&kfull[((size_t)bh * KVLEN + kv) * HD + d0] = o.u;
}

// ---------------------------------------------------------------------------
// vt[b,h,d,kv] = (kv < XL) ? cvt(v_xl fp32) : vbuf bf16. 64x64 LDS transpose.
// ---------------------------------------------------------------------------
__global__ __launch_bounds__(256, 4) void transpose_v(
    const float* __restrict__ v_xl, const u16* __restrict__ vbuf, u16* __restrict__ vt)
{
  __shared__ u16 tile[64 * 72];
  const int tid = threadIdx.x;
  const int kv0 = blockIdx.x * 64;
  const int d0  = blockIdx.y * 64;
  const int bh  = blockIdx.z;
  const int b = bh >> 4, h = bh & 15;
#pragma unroll
  for (int j = 0; j < 2; ++j) {
    const int id = tid + 256 * j;
    const int kr = id >> 3, dq = (id & 7) * 8;
    const int kvg = kv0 + kr;
    if (kvg < XL) {
      const float* src = v_xl + ((size_t)b * XL + kvg) * D_MODEL + h * HD + d0 + dq;
      PrefF32 p; p.load(src, 0);
      *(u32x4*)&tile[kr * 72 + dq] = p.pack();
    } else {
      const u16* src = vbuf + ((size_t)b * TQ + (kvg - XL)) * D_MODEL + h * HD + d0 + dq;
      *(u32x4*)&tile[kr * 72 + dq] = *(const u32x4*)src;
    }
  }
  __syncthreads();
#pragma unroll
  for (int j = 0; j < 2; ++j) {
    const int id = tid + 256 * j;
    const int dr = id >> 3, kq = (id & 7) * 8;
    U4 ov;
#pragma unroll
    for (int i = 0; i < 8; ++i) ov.s[i] = tile[(kq + i) * 72 + dr];
    *(u32x4*)&vt[((size_t)bh * HD + d0 + dr) * KVLEN + kv0 + kq] = ov.u;
  }
}

// ---------------------------------------------------------------------------
// Flash attention. grid (16 qt, 32 bh), 256 thr = 4 waves x 16 q-rows each.
// kv-tile 128. K/V staging = pure bf16 copies. P overlays sK (per-wave rows).
// LDS 69.6 KB -> 2 blocks/CU (8 waves). Rope on Q fused at load.
// ---------------------------------------------------------------------------
#define LSTR 136  // 128 + 8 pad; 272 B row = 17x16B, keeps b128 alignment

__global__ __launch_bounds__(256, 2) void attn(
    const u16* __restrict__ q, const u16* __restrict__ kfull,
    const u16* __restrict__ vt, const float* __restrict__ cosw,
    const float* __restrict__ sinw, const int* __restrict__ iscausal,
    u16* __restrict__ y)
{
  __shared__ u16 sK[128 * LSTR];  // K tile; P overlay (per-wave 16 rows) after S
  __shared__ u16 sV[128 * LSTR];  // V^T tile (rows = d)

  const int tid  = threadIdx.x;
  const int lane = tid & 63;
  const int w    = tid >> 6;
  const int quad = lane >> 4;
  const int mcol = lane & 15;
  const int qt = blockIdx.x;
  const int bh = blockIdx.y;
  const int b = bh >> 4, h = bh & 15;
  const int causal = *iscausal;
  const float SC = 0.08838834764831845f;  // 1/sqrt(128)

  // ---- Q fragments with fused rope (A-layout: m = mcol, k = quad*8 + ks*32)
  bf16x8 qf[4];
  {
    const int trow = qt * 64 + w * 16 + mcol;
    const u16* qrow = q + ((size_t)b * TQ + trow) * D_MODEL + h * HD;
    const float* crow = cosw + trow * 64;
    const float* srow = sinw + trow * 64;
#pragma unroll
    for (int ks = 0; ks < 4; ++ks) {
      const int d0 = ks * 32 + quad * 8;
      U4 qv; qv.u = *(const u32x4*)(qrow + d0);
      f32x4 cv = *(const f32x4*)(crow + (d0 >> 1));
      f32x4 sv = *(const f32x4*)(srow + (d0 >> 1));
      bf16x8 dst;
#pragma unroll
      for (int p = 0; p < 4; ++p) {
        const float e = b2f(qv.s[2 * p]), o = b2f(qv.s[2 * p + 1]);
        dst[2 * p]     = (short)f2b(e * cv[p] - o * sv[p]);
        dst[2 * p + 1] = (short)f2b(e * sv[p] + o * cv[p]);
      }
      qf[ks] = dst;
    }
  }

  f32x4 oacc[8] = {};
  float mrun[4], lrun[4];
#pragma unroll
  for (int r = 0; r < 4; ++r) { mrun[r] = -3.0e38f; lrun[r] = 0.f; }

  for (int t16 = 0; t16 < 16; ++t16) {
    const int kv0 = t16 * 128;
    __syncthreads();  // previous iteration's PV reads done before restaging

    // ---- stage K tile: pure copy from kfull (row = kv, col = d)
#pragma unroll
    for (int j = 0; j < 8; ++j) {
      const int id = tid + 256 * j;
      const int row = id >> 4, c8 = (id & 15) * 8;
      *(u32x4*)&sK[row * LSTR + c8] =
          *(const u32x4*)(kfull + ((size_t)bh * KVLEN + kv0 + row) * HD + c8);
    }
    // ---- stage V^T tile: pure copy from vt (row = d, col = kv)
#pragma unroll
    for (int j = 0; j < 8; ++j) {
      const int id = tid + 256 * j;
      const int dr = id >> 4, c8 = (id & 15) * 8;
      *(u32x4*)&sV[dr * LSTR + c8] =
          *(const u32x4*)(vt + ((size_t)bh * HD + dr) * KVLEN + kv0 + c8);
    }
    __syncthreads();

    // ---- S = Q K^T (8 n-tiles x 4 k-steps)
    f32x4 s[8] = {};
#pragma unroll
    for (int ks = 0; ks < 4; ++ks) {
      const int cc = ks * 4 + quad;
#pragma unroll
      for (int nt = 0; nt < 8; ++nt) {
        bf16x8 kf = *(const bf16x8*)&sK[(nt * 16 + mcol) * LSTR + cc * 8];
        s[nt] = __builtin_amdgcn_mfma_f32_16x16x32_bf16(qf[ks], kf, s[nt], 0, 0, 0);
      }
    }
#pragma unroll
    for (int nt = 0; nt < 8; ++nt)
#pragma unroll
      for (int r = 0; r < 4; ++r) s[nt][r] *= SC;
    if (causal) {
#pragma unroll
      for (int r = 0; r < 4; ++r) {
        const int qi = qt * 64 + w * 16 + quad * 4 + r;
#pragma unroll
        for (int nt = 0; nt < 8; ++nt) {
          const int ki = kv0 + nt * 16 + mcol;
          if (ki > qi + (KVLEN - TQ)) s[nt][r] = -1.0e30f;
        }
      }
    }

    // ---- online softmax (register-only; row = quad*4+r in C layout)
#pragma unroll
    for (int r = 0; r < 4; ++r) {
      float tm = -3.0e38f;
#pragma unroll
      for (int nt = 0; nt < 8; ++nt) tm = fmaxf(tm, s[nt][r]);
      tm = rmax16(tm);
      const float mo = mrun[r];
      const float mn = fmaxf(mo, tm);
      mrun[r] = mn;
      const float al = __expf(mo - mn);
      float rs = 0.f;
#pragma unroll
      for (int nt = 0; nt < 8; ++nt) {
        const float p = __expf(s[nt][r] - mn);
        s[nt][r] = p;
        rs += p;
      }
      rs = rsum16(rs);
      lrun[r] = lrun[r] * al + rs;
#pragma unroll
      for (int nd = 0; nd < 8; ++nd) oacc[nd][r] *= al;
    }
    __syncthreads();  // all waves' S reads of sK done -> safe to overlay P

    // ---- write P (bf16) into own wave's sK rows (row = q-row, col = kv)
    u16* sPw = &sK[w * 16 * LSTR];
#pragma unroll
    for (int r = 0; r < 4; ++r) {
      const int row = quad * 4 + r;
#pragma unroll
      for (int nt = 0; nt < 8; ++nt)
        sPw[row * LSTR + nt * 16 + mcol] = f2b(s[nt][r]);
    }
    // wave-local write->read on same LDS array: compiler inserts lgkmcnt wait

    // ---- O += P V
#pragma unroll
    for (int ks = 0; ks < 4; ++ks) {
      const int cc = ks * 4 + quad;
      bf16x8 pa = *(const bf16x8*)&sPw[mcol * LSTR + cc * 8];
#pragma unroll
      for (int nd = 0; nd < 8; ++nd) {
        bf16x8 vf = *(const bf16x8*)&sV[(nd * 16 + mcol) * LSTR + cc * 8];
        oacc[nd] = __builtin_amdgcn_mfma_f32_16x16x32_bf16(pa, vf, oacc[nd], 0, 0, 0);
      }
    }
  }

  // ---- epilogue: y[b, t, h*HD + d] = O / l (bf16)
#pragma unroll
  for (int r = 0; r < 4; ++r) {
    const int trow = qt * 64 + w * 16 + quad * 4 + r;
    const float inv = 1.0f / lrun[r];
    u16* yr = y + ((size_t)b * TQ + trow) * D_MODEL + h * HD;
#pragma unroll
    for (int nd = 0; nd < 8; ++nd)
      yr[nd * 16 + mcol] = f2b(oacc[nd][r] * inv);
  }
}

// ---------------------------------------------------------------------------
extern "C" void kernel_launch(void* const* d_in, const int* in_sizes, int n_in,
                              void* d_out, int out_size, void* d_ws, size_t ws_size,
                              hipStream_t stream) {
  const float* x      = (const float*)d_in[0];
  const float* cosw   = (const float*)d_in[1];
  const float* sinw   = (const float*)d_in[2];
  const float* k_xl   = (const float*)d_in[3];
  const float* v_xl   = (const float*)d_in[4];
  const float* pos    = (const float*)d_in[5];
  const float* w_qkv  = (const float*)d_in[6];
  const float* w_proj = (const float*)d_in[7];
  const int* isc      = (const int*)d_in[8];
  float* out = (float*)d_out;

  // ws layout (sequential-reuse safe; 58.7 MB total):
  //   qbuf  @ 0         8,388,608   (gemm1 out, attn in)
  //   kbuf  @ 8388608   8,388,608   (gemm1 out, prep_k in) -> reused as y_ws
  //   vbuf  @ 16777216  8,388,608   (gemm1 out, transpose_v in)
  //   wqb   @ 25165824  25,165,824  (cvt out, gemm1 in; dead after)
  //   kfull @ 25165824  16,777,216  (overlays wqb; prep_k out, attn in)
  //   vt    @ 41943040  16,777,216  (overlays wqb tail; transpose_v out)
  char* ws = (char*)d_ws;
  u16* qbuf  = (u16*)ws;
  u16* kbuf  = (u16*)(ws + (size_t)8388608);
  u16* vbuf  = (u16*)(ws + (size_t)16777216);
  u16* wqb   = (u16*)(ws + (size_t)25165824);
  u16* kfull = (u16*)(ws + (size_t)25165824);
  u16* vt    = (u16*)(ws + (size_t)41943040);
  u16* y_ws  = kbuf;

  // 1) w_qkv fp32 -> bf16 (12,582,912 elems / 8 per thread)
  cvt_bf16<<<6144, 256, 0, stream>>>(w_qkv, wqb);

  // 2) q/k/v = x @ w_qkv^T  (A fp32 manual, B bf16 async, C split bf16)
  dim3 g1(48, 16);
  gemm_bt<true, false, true><<<g1, 256, 0, stream>>>(
      x, wqb, qbuf, kbuf, vbuf, 2048, 6144, 2048);

  // 3) kfull[b,h,kv,d] (pos-add for XL, rope for local)
  prep_k<<<4096, 256, 0, stream>>>(k_xl, pos, kbuf, cosw, sinw, kfull);

  // 4) vt[b,h,d,kv]
  dim3 gt(KVLEN / 64, HD / 64, BSZ * NHEADS);
  transpose_v<<<gt, 256, 0, stream>>>(v_xl, vbuf, vt);

  // 5) flash attention -> y bf16 (b,t,c); y overlays kbuf (dead after prep_k)
  dim3 ga(16, BSZ * NHEADS);
  attn<<<ga, 256, 0, stream>>>(qbuf, kfull, vt, cosw, sinw, isc, y_ws);

  // 6) out = y @ w_proj^T  (A bf16 async, B fp32 manual, C fp32)
  dim3 g2(16, 16);
  gemm_bt<false, true, false><<<g2, 256, 0, stream>>>(
      y_ws, w_proj, out, nullptr, nullptr, 2048, 2048, 2048);
}

// Round 6
// 350.584 us; speedup vs baseline: 1.3277x; 1.1134x over previous
//
#include <hip/hip_runtime.h>
#include <stdint.h>

typedef unsigned short u16;
typedef __attribute__((ext_vector_type(4))) float f32x4;
typedef __attribute__((ext_vector_type(8))) short bf16x8;
typedef __attribute__((ext_vector_type(4))) uint32_t u32x4;

#define D_MODEL 2048
#define NHEADS 16
#define HD 128
#define BSZ 2
#define TQ 1024
#define XL 1024
#define KVLEN 2048

__device__ __forceinline__ float b2f(u16 u) {
  union { uint32_t i; float f; } x; x.i = ((uint32_t)u) << 16; return x.f;
}
__device__ __forceinline__ u16 f2b(float f) {
  union { float f; uint32_t i; } x; x.f = f;
  uint32_t r = x.i + 0x7FFFu + ((x.i >> 16) & 1u);  // RNE
  return (u16)(r >> 16);
}

union U4 { u32x4 u; u16 s[8]; };

__device__ __forceinline__ void async_copy16(const u16* g, u16* l) {
  __builtin_amdgcn_global_load_lds((__attribute__((address_space(1))) void*)g,
                                   (__attribute__((address_space(3))) void*)l,
                                   16, 0, 0);
}

__device__ __forceinline__ float rmax16(float v) {
  v = fmaxf(v, __shfl_xor(v, 1));
  v = fmaxf(v, __shfl_xor(v, 2));
  v = fmaxf(v, __shfl_xor(v, 4));
  v = fmaxf(v, __shfl_xor(v, 8));
  return v;
}
__device__ __forceinline__ float rsum16(float v) {
  v += __shfl_xor(v, 1);
  v += __shfl_xor(v, 2);
  v += __shfl_xor(v, 4);
  v += __shfl_xor(v, 8);
  return v;
}

struct PrefF32 {  // 8 fp32 -> 8 bf16 pack
  f32x4 lo, hi;
  __device__ __forceinline__ void load(const float* base, size_t off) {
    lo = *(const f32x4*)(base + off);
    hi = *(const f32x4*)(base + off + 4);
  }
  __device__ __forceinline__ u32x4 pack() const {
    U4 o;
    o.s[0] = f2b(lo[0]); o.s[1] = f2b(lo[1]); o.s[2] = f2b(lo[2]); o.s[3] = f2b(lo[3]);
    o.s[4] = f2b(hi[0]); o.s[5] = f2b(hi[1]); o.s[6] = f2b(hi[2]); o.s[7] = f2b(hi[3]);
    return o.u;
  }
};

// ---------------------------------------------------------------------------
// fp32 -> bf16 elementwise, 8 elems/thread
// ---------------------------------------------------------------------------
__global__ __launch_bounds__(256, 4) void cvt_bf16(
    const float* __restrict__ src, u16* __restrict__ dst)
{
  const size_t id = (size_t)blockIdx.x * 256 + threadIdx.x;
  PrefF32 p; p.load(src, id * 8);
  *(u32x4*)&dst[id * 8] = p.pack();
}

// ---------------------------------------------------------------------------
// C = A * Bt^T, all-bf16 m97 structure: 128xBN tile, BK=32, 256 thr (2x2
// waves), 16x16x32 MFMA, async global_load_lds width=16 both operands.
// BN = 128 (gemm1) or 64 (gemm2: 2x blocks for the small-N shape).
// CSPLIT: C bf16 routed to one of 3 buffers (stride 2048); else C fp32.
// ---------------------------------------------------------------------------
template <int BN, bool CSPLIT>
__global__ __launch_bounds__(256, 2) void gemm_bt(
    const u16* __restrict__ A, const u16* __restrict__ B,
    void* __restrict__ C0, void* __restrict__ C1, void* __restrict__ C2,
    int M, int N, int K)
{
  constexpr int JN = BN / 32;  // n-frags per wave
  __shared__ u16 sA[128 * 32];
  __shared__ u16 sB[BN * 32];
  const int tid  = threadIdx.x;
  const int lane = tid & 63;
  const int wave = tid >> 6;
  const int quad = lane >> 4;
  const int mcol = lane & 15;
  const int wm = (wave >> 1) * 64;
  const int wn = (wave & 1) * (BN / 2);
  const int bm = blockIdx.y * 128;
  const int bnE = blockIdx.x * BN;

  f32x4 acc[4][JN] = {};

  // chunk c (8 elems, 16B) at LDS c*8: row = c>>2, kq = (c&3)*8
  const int c0 = tid, c1 = tid + 256;
  size_t a0 = (size_t)(bm + (c0 >> 2)) * K + (c0 & 3) * 8;
  size_t a1 = (size_t)(bm + (c1 >> 2)) * K + (c1 & 3) * 8;
  size_t b0 = (size_t)(bnE + (c0 >> 2)) * K + (c0 & 3) * 8;
  size_t b1 = (BN == 128) ? (size_t)(bnE + (c1 >> 2)) * K + (c1 & 3) * 8 : 0;

  const int nk = K >> 5;
  for (int kk = 0; kk < nk; ++kk) {
    async_copy16(A + a0, &sA[c0 * 8]);
    async_copy16(A + a1, &sA[c1 * 8]);
    async_copy16(B + b0, &sB[c0 * 8]);
    if (BN == 128) async_copy16(B + b1, &sB[c1 * 8]);
    a0 += 32; a1 += 32; b0 += 32; b1 += 32;
    __syncthreads();  // drains vmcnt (global_load_lds) before frag reads
    bf16x8 af[4], bff[JN];
#pragma unroll
    for (int i = 0; i < 4; ++i)
      af[i] = *(const bf16x8*)&sA[(wm + i * 16 + mcol) * 32 + quad * 8];
#pragma unroll
    for (int j = 0; j < JN; ++j)
      bff[j] = *(const bf16x8*)&sB[(wn + j * 16 + mcol) * 32 + quad * 8];
#pragma unroll
    for (int i = 0; i < 4; ++i)
#pragma unroll
      for (int j = 0; j < JN; ++j)
        acc[i][j] = __builtin_amdgcn_mfma_f32_16x16x32_bf16(af[i], bff[j], acc[i][j], 0, 0, 0);
    __syncthreads();  // frag reads done before next staging
  }

  // epilogue: C row = quad*4 + reg, col = mcol (m89-verified C/D layout)
  if (CSPLIT) {
    const int sel = bnE >> 11;
    u16* Cp = (u16*)(sel == 0 ? C0 : (sel == 1 ? C1 : C2));
    const int bnl = (bnE & 2047) + wn;
#pragma unroll
    for (int i = 0; i < 4; ++i)
#pragma unroll
      for (int r = 0; r < 4; ++r) {
        const size_t base = (size_t)(bm + wm + i * 16 + quad * 4 + r) * 2048 + bnl;
#pragma unroll
        for (int j = 0; j < JN; ++j)
          Cp[base + j * 16 + mcol] = f2b(acc[i][j][r]);
      }
  } else {
    float* Cp = (float*)C0;
#pragma unroll
    for (int i = 0; i < 4; ++i)
#pragma unroll
      for (int r = 0; r < 4; ++r) {
        const size_t base = (size_t)(bm + wm + i * 16 + quad * 4 + r) * N + bnE + wn;
#pragma unroll
        for (int j = 0; j < JN; ++j)
          Cp[base + j * 16 + mcol] = acc[i][j][r];
      }
  }
}

// ---------------------------------------------------------------------------
// kfull[b,h,kv,d]: kv<XL -> bf16(kxl + pos); kv>=XL -> rope(kbuf) with cos/sin.
// ---------------------------------------------------------------------------
__global__ __launch_bounds__(256, 4) void prep_k(
    const float* __restrict__ kxl, const float* __restrict__ pos,
    const u16* __restrict__ kbuf, const float* __restrict__ cosw,
    const float* __restrict__ sinw, u16* __restrict__ kfull)
{
  const int id = blockIdx.x * 256 + threadIdx.x;
  const int dc = id & 15;
  const int kv = (id >> 4) & 2047;
  const int bh = id >> 15;
  const int b = bh >> 4, h = bh & 15;
  const int d0 = dc * 8;
  U4 o;
  if (kv < XL) {
    const float* kp = kxl + ((size_t)b * XL + kv) * D_MODEL + h * HD + d0;
    const float* pp = pos + (size_t)kv * D_MODEL + h * HD + d0;
    f32x4 kl = *(const f32x4*)kp, kh = *(const f32x4*)(kp + 4);
    f32x4 pl = *(const f32x4*)pp, ph = *(const f32x4*)(pp + 4);
#pragma unroll
    for (int p = 0; p < 4; ++p) {
      o.s[p]     = f2b(kl[p] + pl[p]);
      o.s[4 + p] = f2b(kh[p] + ph[p]);
    }
  } else {
    const int tq = kv - XL;
    U4 kv_;
    kv_.u = *(const u32x4*)(kbuf + ((size_t)b * TQ + tq) * D_MODEL + h * HD + d0);
    f32x4 cv = *(const f32x4*)(cosw + tq * 64 + (d0 >> 1));
    f32x4 sv = *(const f32x4*)(sinw + tq * 64 + (d0 >> 1));
#pragma unroll
    for (int p = 0; p < 4; ++p) {
      const float e = b2f(kv_.s[2 * p]), od = b2f(kv_.s[2 * p + 1]);
      o.s[2 * p]     = f2b(e * cv[p] - od * sv[p]);
      o.s[2 * p + 1] = f2b(e * sv[p] + od * cv[p]);
    }
  }
  *(u32x4*)&kfull[((size_t)bh * KVLEN + kv) * HD + d0] = o.u;
}

// ---------------------------------------------------------------------------
// vt[b,h,d,kv] = (kv < XL) ? cvt(v_xl fp32) : vbuf bf16. 64x64 LDS transpose.
// ---------------------------------------------------------------------------
__global__ __launch_bounds__(256, 4) void transpose_v(
    const float* __restrict__ v_xl, const u16* __restrict__ vbuf, u16* __restrict__ vt)
{
  __shared__ u16 tile[64 * 72];
  const int tid = threadIdx.x;
  const int kv0 = blockIdx.x * 64;
  const int d0  = blockIdx.y * 64;
  const int bh  = blockIdx.z;
  const int b = bh >> 4, h = bh & 15;
#pragma unroll
  for (int j = 0; j < 2; ++j) {
    const int id = tid + 256 * j;
    const int kr = id >> 3, dq = (id & 7) * 8;
    const int kvg = kv0 + kr;
    if (kvg < XL) {
      const float* src = v_xl + ((size_t)b * XL + kvg) * D_MODEL + h * HD + d0 + dq;
      PrefF32 p; p.load(src, 0);
      *(u32x4*)&tile[kr * 72 + dq] = p.pack();
    } else {
      const u16* src = vbuf + ((size_t)b * TQ + (kvg - XL)) * D_MODEL + h * HD + d0 + dq;
      *(u32x4*)&tile[kr * 72 + dq] = *(const u32x4*)src;
    }
  }
  __syncthreads();
#pragma unroll
  for (int j = 0; j < 2; ++j) {
    const int id = tid + 256 * j;
    const int dr = id >> 3, kq = (id & 7) * 8;
    U4 ov;
#pragma unroll
    for (int i = 0; i < 8; ++i) ov.s[i] = tile[(kq + i) * 72 + dr];
    *(u32x4*)&vt[((size_t)bh * HD + d0 + dr) * KVLEN + kv0 + kq] = ov.u;
  }
}

// ---------------------------------------------------------------------------
// Flash attention. grid (16 qt, 32 bh), 256 thr = 4 waves x 16 q-rows each.
// kv-tile 128. Register prefetch of next K/V tile hides global latency.
// P overlays sK per-wave rows. LDS 69.6 KB -> 2 blocks/CU. 1/sqrt(d) folded
// into Q fragments at rope time.
// ---------------------------------------------------------------------------
#define LSTR 136  // 128 + 8 pad; keeps 16B alignment of 8-elem chunks

__global__ __launch_bounds__(256, 2) void attn(
    const u16* __restrict__ q, const u16* __restrict__ kfull,
    const u16* __restrict__ vt, const float* __restrict__ cosw,
    const float* __restrict__ sinw, const int* __restrict__ iscausal,
    u16* __restrict__ y)
{
  __shared__ u16 sK[128 * LSTR];  // K tile; P overlay (per-wave 16 rows) after S
  __shared__ u16 sV[128 * LSTR];  // V^T tile (rows = d)

  const int tid  = threadIdx.x;
  const int lane = tid & 63;
  const int w    = tid >> 6;
  const int quad = lane >> 4;
  const int mcol = lane & 15;
  const int qt = blockIdx.x;
  const int bh = blockIdx.y;
  const int b = bh >> 4, h = bh & 15;
  const int causal = *iscausal;
  const float SC = 0.08838834764831845f;  // 1/sqrt(128)

  // ---- Q fragments with fused rope, pre-scaled by SC (A-layout)
  bf16x8 qf[4];
  {
    const int trow = qt * 64 + w * 16 + mcol;
    const u16* qrow = q + ((size_t)b * TQ + trow) * D_MODEL + h * HD;
    const float* crow = cosw + trow * 64;
    const float* srow = sinw + trow * 64;
#pragma unroll
    for (int ks = 0; ks < 4; ++ks) {
      const int d0 = ks * 32 + quad * 8;
      U4 qv; qv.u = *(const u32x4*)(qrow + d0);
      f32x4 cv = *(const f32x4*)(crow + (d0 >> 1));
      f32x4 sv = *(const f32x4*)(srow + (d0 >> 1));
      bf16x8 dst;
#pragma unroll
      for (int p = 0; p < 4; ++p) {
        const float e = b2f(qv.s[2 * p]), o = b2f(qv.s[2 * p + 1]);
        dst[2 * p]     = (short)f2b((e * cv[p] - o * sv[p]) * SC);
        dst[2 * p + 1] = (short)f2b((e * sv[p] + o * cv[p]) * SC);
      }
      qf[ks] = dst;
    }
  }

  // staging coords: chunk j covers row (tid>>4)+16j, bytes (tid&15)*16
  const int srow = tid >> 4;
  const int sc8 = (tid & 15) * 8;
  const u16* kbase = kfull + (size_t)bh * KVLEN * HD;
  const u16* vbase = vt + (size_t)bh * HD * KVLEN;

  u32x4 kreg[8], vreg[8];
#define LOADT(KV0)                                                          \
  do {                                                                      \
    _Pragma("unroll") for (int j = 0; j < 8; ++j) {                         \
      const int rr = srow + 16 * j;                                         \
      kreg[j] = *(const u32x4*)(kbase + ((size_t)(KV0) + rr) * HD + sc8);   \
      vreg[j] = *(const u32x4*)(vbase + (size_t)rr * KVLEN + (KV0) + sc8);  \
    }                                                                       \
  } while (0)

  f32x4 oacc[8] = {};
  float mrun[4], lrun[4];
#pragma unroll
  for (int r = 0; r < 4; ++r) { mrun[r] = -3.0e38f; lrun[r] = 0.f; }

  LOADT(0);
  for (int t16 = 0; t16 < 16; ++t16) {
    __syncthreads();  // previous iteration's LDS reads done before restaging
#pragma unroll
    for (int j = 0; j < 8; ++j) {
      const int rr = srow + 16 * j;
      *(u32x4*)&sK[rr * LSTR + sc8] = kreg[j];
      *(u32x4*)&sV[rr * LSTR + sc8] = vreg[j];
    }
    __syncthreads();  // staging visible
    if (t16 < 15) LOADT((t16 + 1) * 128);  // prefetch next tile (hides latency)

    const int kv0 = t16 * 128;

    // ---- S = Q K^T (8 n-tiles x 4 k-steps); Q pre-scaled
    f32x4 s[8] = {};
#pragma unroll
    for (int ks = 0; ks < 4; ++ks) {
      const int cc = ks * 4 + quad;
#pragma unroll
      for (int nt = 0; nt < 8; ++nt) {
        bf16x8 kf = *(const bf16x8*)&sK[(nt * 16 + mcol) * LSTR + cc * 8];
        s[nt] = __builtin_amdgcn_mfma_f32_16x16x32_bf16(qf[ks], kf, s[nt], 0, 0, 0);
      }
    }
    if (causal) {
#pragma unroll
      for (int r = 0; r < 4; ++r) {
        const int qi = qt * 64 + w * 16 + quad * 4 + r;
#pragma unroll
        for (int nt = 0; nt < 8; ++nt) {
          const int ki = kv0 + nt * 16 + mcol;
          if (ki > qi + (KVLEN - TQ)) s[nt][r] = -1.0e30f;
        }
      }
    }

    // ---- online softmax (register-only; row = quad*4+r in C layout)
#pragma unroll
    for (int r = 0; r < 4; ++r) {
      float tm = -3.0e38f;
#pragma unroll
      for (int nt = 0; nt < 8; ++nt) tm = fmaxf(tm, s[nt][r]);
      tm = rmax16(tm);
      const float mo = mrun[r];
      const float mn = fmaxf(mo, tm);
      mrun[r] = mn;
      const float al = __expf(mo - mn);
      float rs = 0.f;
#pragma unroll
      for (int nt = 0; nt < 8; ++nt) {
        const float p = __expf(s[nt][r] - mn);
        s[nt][r] = p;
        rs += p;
      }
      rs = rsum16(rs);
      lrun[r] = lrun[r] * al + rs;
#pragma unroll
      for (int nd = 0; nd < 8; ++nd) oacc[nd][r] *= al;
    }
    __syncthreads();  // all waves' S reads of sK done -> safe to overlay P

    // ---- write P (bf16) into own wave's sK rows (row = q-row, col = kv)
    u16* sPw = &sK[w * 16 * LSTR];
#pragma unroll
    for (int r = 0; r < 4; ++r) {
      const int row = quad * 4 + r;
#pragma unroll
      for (int nt = 0; nt < 8; ++nt)
        sPw[row * LSTR + nt * 16 + mcol] = f2b(s[nt][r]);
    }
    // wave-local write->read: compiler inserts lgkmcnt wait

    // ---- O += P V
#pragma unroll
    for (int ks = 0; ks < 4; ++ks) {
      const int cc = ks * 4 + quad;
      bf16x8 pa = *(const bf16x8*)&sPw[mcol * LSTR + cc * 8];
#pragma unroll
      for (int nd = 0; nd < 8; ++nd) {
        bf16x8 vf = *(const bf16x8*)&sV[(nd * 16 + mcol) * LSTR + cc * 8];
        oacc[nd] = __builtin_amdgcn_mfma_f32_16x16x32_bf16(pa, vf, oacc[nd], 0, 0, 0);
      }
    }
  }
#undef LOADT

  // ---- epilogue: y[b, t, h*HD + d] = O / l (bf16)
#pragma unroll
  for (int r = 0; r < 4; ++r) {
    const int trow = qt * 64 + w * 16 + quad * 4 + r;
    const float inv = 1.0f / lrun[r];
    u16* yr = y + ((size_t)b * TQ + trow) * D_MODEL + h * HD;
#pragma unroll
    for (int nd = 0; nd < 8; ++nd)
      yr[nd * 16 + mcol] = f2b(oacc[nd][r] * inv);
  }
}

// ---------------------------------------------------------------------------
extern "C" void kernel_launch(void* const* d_in, const int* in_sizes, int n_in,
                              void* d_out, int out_size, void* d_ws, size_t ws_size,
                              hipStream_t stream) {
  const float* x      = (const float*)d_in[0];
  const float* cosw   = (const float*)d_in[1];
  const float* sinw   = (const float*)d_in[2];
  const float* k_xl   = (const float*)d_in[3];
  const float* v_xl   = (const float*)d_in[4];
  const float* pos    = (const float*)d_in[5];
  const float* w_qkv  = (const float*)d_in[6];
  const float* w_proj = (const float*)d_in[7];
  const int* isc      = (const int*)d_in[8];
  float* out = (float*)d_out;

  // ws layout (58.7 MB, overlap-safe by stream order):
  //   qbuf  @ 0          8.4M  (gemm1 out, attn in)
  //   kbuf  @ 8388608    8.4M  (gemm1 out, prep_k in) -> y_ws after prep_k
  //   vbuf  @ 16777216   8.4M  (gemm1 out, transpose_v in)
  //   wqb   @ 25165824  25.2M  (cvt out, gemm1 in; dead after gemm1)
  //   kfull @ 25165824  16.8M  (prep_k out, attn in; overlays dead wqb)
  //   wpb   @ 25165824   8.4M  (cvt AFTER attn; overlays dead kfull)
  //   vt    @ 41943040  16.8M  (transpose_v out after gemm1; overlays wqb tail)
  //   xb    @ 50331648   8.4M  (cvt out, gemm1 in; overwritten by vt tail later)
  char* ws = (char*)d_ws;
  u16* qbuf  = (u16*)ws;
  u16* kbuf  = (u16*)(ws + (size_t)8388608);
  u16* vbuf  = (u16*)(ws + (size_t)16777216);
  u16* wqb   = (u16*)(ws + (size_t)25165824);
  u16* kfull = (u16*)(ws + (size_t)25165824);
  u16* wpb   = (u16*)(ws + (size_t)25165824);
  u16* vt    = (u16*)(ws + (size_t)41943040);
  u16* xb    = (u16*)(ws + (size_t)50331648);
  u16* y_ws  = kbuf;

  // 1) x fp32 -> bf16 (4,194,304 elems)
  cvt_bf16<<<2048, 256, 0, stream>>>(x, xb);
  // 2) w_qkv fp32 -> bf16 (12,582,912 elems)
  cvt_bf16<<<6144, 256, 0, stream>>>(w_qkv, wqb);

  // 3) q/k/v = x @ w_qkv^T  (all-bf16 async, C split bf16)
  dim3 g1(48, 16);
  gemm_bt<128, true><<<g1, 256, 0, stream>>>(xb, wqb, qbuf, kbuf, vbuf, 2048, 6144, 2048);

  // 4) kfull[b,h,kv,d]
  prep_k<<<4096, 256, 0, stream>>>(k_xl, pos, kbuf, cosw, sinw, kfull);

  // 5) vt[b,h,d,kv]
  dim3 gt(KVLEN / 64, HD / 64, BSZ * NHEADS);
  transpose_v<<<gt, 256, 0, stream>>>(v_xl, vbuf, vt);

  // 6) flash attention -> y bf16 (b,t,c)
  dim3 ga(16, BSZ * NHEADS);
  attn<<<ga, 256, 0, stream>>>(qbuf, kfull, vt, cosw, sinw, isc, y_ws);

  // 7) w_proj fp32 -> bf16 (after attn: wpb overlays dead kfull)
  cvt_bf16<<<2048, 256, 0, stream>>>(w_proj, wpb);

  // 8) out = y @ w_proj^T  (all-bf16 async, 128x64 tiles -> 512 blocks, C fp32)
  dim3 g2(32, 16);
  gemm_bt<64, false><<<g2, 256, 0, stream>>>(y_ws, wpb, out, nullptr, nullptr, 2048, 2048, 2048);
}